// Round 12
// baseline (411.750 us; speedup 1.0000x reference)
//
#include <hip/hip_runtime.h>
#include <hip/hip_bf16.h>
#include <cstdint>
#include <cstddef>

// Problem constants
static constexpr int B   = 1024;
static constexpr int N   = 64;
static constexpr int BN  = B * N;      // 65536 nodes
static constexpr int EPG = 192;
static constexpr int E   = B * EPG;    // 196608 edges
static constexpr int FP  = 608;        // padded feature dim (mult of 32)
static constexpr int KP1 = 320;        // conv1 K (PX0 cols, padded)
static constexpr int PMS = 72;         // Pm row stride (bf16): 144B -> conflict-free
static constexpr int NCONV = 2560;     // conv blocks per conv dispatch

typedef __hip_bfloat16 bf16;
typedef __bf16 bf16x8 __attribute__((ext_vector_type(8)));
typedef __bf16 bf16x4 __attribute__((ext_vector_type(4)));
typedef float  f32x4  __attribute__((ext_vector_type(4)));

__device__ __forceinline__ void storeC(float* p, float v) { *p = v; }
__device__ __forceinline__ void storeC(bf16* p, float v) { *p = __float2bfloat16(v); }

// async global->LDS, 16B per lane; LDS dest is wave-uniform base + lane*16
__device__ __forceinline__ void llds16(const void* g, void* l) {
    __builtin_amdgcn_global_load_lds(
        (const __attribute__((address_space(1))) unsigned int*)g,
        (__attribute__((address_space(3))) unsigned int*)l,
        16, 0, 0);
}

#define RAW_BARRIER() do { __builtin_amdgcn_s_barrier(); \
                           asm volatile("" ::: "memory"); } while (0)

// ===========================================================================
// R11 schedule (2-barrier counted vmcnt, last-iter exact waits) + NEW:
// conv kernels keep ONLY A in LDS (B = weights, L2-hot, read global->VGPR
// with register double-buffer bgA/bgB, loop unrolled by 2 for static reg
// selection).  Halves per-block-iter LDS traffic (48KB -> 24KB), which the
// R2..R11 invariance analysis identifies as the binding resource.
//   body(k): bar#1 -> [loadB(k+1)x4 ; stageA(k+1)x2] -> vmcnt(6) (drains
//   B(k)+A(k), keeps 6 in flight) -> bar#2 -> ds_read af + 16 MFMA w/ bg(k).
//   Last iter: conv1 vmcnt(0); conv_fused queues Pm behind -> vmcnt(4).
// LDS tile swizzle (BK=32, 64B rows): slot(row,s) holds chunk s^((row>>1)&3);
// read offset co = (lhi ^ ((l15>>1)&3))*8 elems -> conflict-free b128 reads.
// ===========================================================================

// ---------------------------------------------------------------------------
// 4-wave 64x128 tile body (256 threads) — R11-proven (unchanged).
// lds: buf0 [0,12K), buf1 [12K,24K).  Stage = 3 vm-instructions/wave.
// ---------------------------------------------------------------------------
template<bool RELU, bool FILM, typename CT>
__device__ __forceinline__ void g64_tile(
    const bf16* __restrict__ A, int lda,
    const bf16* __restrict__ Bt, int ldb,
    const float* __restrict__ bias,
    CT* __restrict__ C, int ldc, int Ncap,
    const bf16* __restrict__ fS, const bf16* __restrict__ fT, int fstride,
    int K, int m0, int n0, char* lds, int tid)
{
    const int lane = tid & 63;
    const int w    = tid >> 6;
    const int wn   = w * 32;
    const int l15  = lane & 15;
    const int lhi  = lane >> 4;
    const int co   = (lhi ^ ((l15 >> 1) & 3)) << 3;
    const int nk   = K >> 5;

    auto stage = [&](int k0, char* buf) {
        {   // A tile: 64 rows x 4 chunks = 256
            int row = tid >> 2;
            int kc  = (tid & 3) ^ ((row >> 1) & 3);
            llds16(A + (size_t)(m0 + row) * lda + k0 + kc * 8,
                   buf + (size_t)(w * 64) * 16);
        }
        #pragma unroll
        for (int t = 0; t < 2; ++t) {   // B tile: 128 rows = 512 chunks
            int ci  = t * 256 + tid;
            int row = ci >> 2;
            int kc  = (ci & 3) ^ ((row >> 1) & 3);
            llds16(Bt + (size_t)(n0 + row) * ldb + k0 + kc * 8,
                   buf + 4096 + (size_t)(t * 256 + w * 64) * 16);
        }
    };

    f32x4 acc[4][2] = {};
    stage(0, lds);
    asm volatile("s_waitcnt vmcnt(0)" ::: "memory");
    __syncthreads();

    for (int k = 0; k < nk; ++k) {
        RAW_BARRIER();                                   // #1: buf[(k+1)&1] free
        if (k + 1 < nk) {
            stage((k + 1) << 5, lds + ((k + 1) & 1) * 12288);
            asm volatile("s_waitcnt vmcnt(3)" ::: "memory"); // drains stage(k)
        } else {
            asm volatile("s_waitcnt vmcnt(0)" ::: "memory"); // last tile landed
        }
        RAW_BARRIER();                                   // #2: visibility

        __bf16* As = (__bf16*)(lds + (k & 1) * 12288);
        __bf16* Bs = As + 2048;
        bf16x8 af[4], bg[2];
        #pragma unroll
        for (int i = 0; i < 4; ++i)
            af[i] = *(bf16x8*)(As + (i * 16 + l15) * 32 + co);
        #pragma unroll
        for (int j = 0; j < 2; ++j)
            bg[j] = *(bf16x8*)(Bs + (wn + j * 16 + l15) * 32 + co);
        #pragma unroll
        for (int i = 0; i < 4; ++i)
            #pragma unroll
            for (int j = 0; j < 2; ++j)
                acc[i][j] = __builtin_amdgcn_mfma_f32_16x16x32_bf16(
                    af[i], bg[j], acc[i][j], 0, 0, 0);
    }
    __syncthreads();   // full drain before epilogue

    #pragma unroll
    for (int i = 0; i < 4; ++i) {
        #pragma unroll
        for (int j = 0; j < 2; ++j) {
            int col = n0 + wn + j * 16 + l15;
            if (col < Ncap) {
                float bv = bias ? bias[col] : 0.f;
                #pragma unroll
                for (int e = 0; e < 4; ++e) {
                    int row = m0 + i * 16 + lhi * 4 + e;
                    float v = acc[i][j][e] + bv;
                    if (RELU) v = fmaxf(v, 0.f);
                    if (FILM) {
                        float sv = __bfloat162float(fS[(size_t)row * fstride + col]);
                        float tv = __bfloat162float(fT[(size_t)row * fstride + col]);
                        v = v * (1.f + sv) + tv;
                    }
                    storeC(&C[(size_t)row * ldc + col], v);
                }
            }
        }
    }
}

// noinline guest wrapper: keeps guest register usage from inflating the host
// conv kernel's VGPR allocation.  Needs 24KB of lds.
__device__ __attribute__((noinline)) void guest_g64(
    const bf16* gA, int glda, const bf16* gBt, int gldb,
    const float* gbias, bf16* gC, int gldc, int gNcap, int gK, int gnt,
    int t, char* lds, int tid)
{
    int mt2 = t / gnt, nt2 = t % gnt;
    g64_tile<true, false, bf16>(gA, glda, gBt, gldb, gbias, gC, gldc, gNcap,
                                nullptr, nullptr, 0, gK, mt2 * 64, nt2 * 128,
                                lds, tid);
}

// standalone 64-row-tile GEMM (h-layers)
template<bool RELU, bool FILM, typename CT>
__global__ __launch_bounds__(256) void gemm64(
    const bf16* __restrict__ A, int lda,
    const bf16* __restrict__ Bt, int ldb,
    const float* __restrict__ bias,
    CT* __restrict__ C, int ldc, int Ncap,
    const bf16* __restrict__ fS, const bf16* __restrict__ fT, int fstride,
    int K)
{
    __shared__ __align__(16) char lds[24576];
    g64_tile<RELU, FILM, CT>(A, lda, Bt, ldb, bias, C, ldc, Ncap,
                             fS, fT, fstride, K,
                             blockIdx.x * 64, blockIdx.y * 128, lds,
                             threadIdx.x);
}

// two independent small GEMMs in one dispatch: EO (384 blocks) + W3 (80)
__global__ __launch_bounds__(256) void k_two_gemms(
    const bf16* __restrict__ A2b, const bf16* __restrict__ Wet,
    const float* __restrict__ b_e, bf16* __restrict__ EO,
    const bf16* __restrict__ Yv, const bf16* __restrict__ Wb3,
    const float* __restrict__ b_c3, bf16* __restrict__ G0)
{
    __shared__ __align__(16) char lds[24576];
    int bid = blockIdx.x;
    if (bid < 384) {
        int mt = bid / 24, nt = bid % 24;
        g64_tile<false, false, bf16>(A2b, 512, Wet, 512, b_e, EO, 3000, 3000,
                                     nullptr, nullptr, 0, 512,
                                     mt * 64, nt * 128, lds, threadIdx.x);
    } else {
        int t = bid - 384;
        int mt = t / 5, nt = t % 5;
        g64_tile<false, false, bf16>(Yv, FP, Wb3, FP, b_c3, G0, FP, 600,
                                     nullptr, nullptr, 0, FP,
                                     mt * 64, nt * 128, lds, threadIdx.x);
    }
}

// ===========================================================================
// conv1 as a PLAIN GEMM: X1 = relu(PX0 @ Wb1^T + b_c1).  128x128 tiles,
// BK=32.  A-only LDS double-buffer (2x8KB); B (weights) in registers with
// double-buffer bgA/bgB; 2-barrier counted vmcnt(6).  + hidden t1 guest.
// lds: bufA0 [0,8K), bufA1 [8K,16K); guest needs 24K -> regA[24576].
// ===========================================================================
__global__ __launch_bounds__(256, 4) void conv1_gemm(
    const bf16* __restrict__ A,        // PX0, lda = KP1
    const bf16* __restrict__ Bt,       // Wb1, ldb = KP1
    const float* __restrict__ bias,
    bf16* __restrict__ X1,
    const bf16* __restrict__ gA, int glda,
    const bf16* __restrict__ gBt, int gldb,
    const float* __restrict__ gbias,
    bf16* __restrict__ gC, int gldc, int gNcap, int gK, int gnt)
{
    __shared__ __align__(16) char regA[24576];
    const int tid = threadIdx.x;
    const int bid = blockIdx.x;

    if (bid >= NCONV) {
        guest_g64(gA, glda, gBt, gldb, gbias, gC, gldc, gNcap, gK, gnt,
                  bid - NCONV, regA, tid);
        return;
    }

    const int lane = tid & 63;
    const int w    = tid >> 6;
    const int wm   = (w & 1) * 64;
    const int wn   = (w >> 1) * 64;
    const int l15  = lane & 15;
    const int lhi  = lane >> 4;
    const int co   = (lhi ^ ((l15 >> 1) & 3)) << 3;

    const int lid = bid >> 3;
    const int mt  = (bid & 7) * 64 + lid / 5;
    const int nt  = lid % 5;
    const int m0  = mt * 128;
    const int n0  = nt * 128;

    auto stageA = [&](int k0, char* buf) {      // 2 vm-instrs per wave
        #pragma unroll
        for (int t = 0; t < 2; ++t) {
            int ci  = t * 256 + tid;
            int row = ci >> 2;
            int kc  = (ci & 3) ^ ((row >> 1) & 3);
            llds16(A + (size_t)(m0 + row) * KP1 + k0 + kc * 8,
                   buf + (size_t)(t * 256 + w * 64) * 16);
        }
    };
    const bf16* bRow = Bt + (size_t)(n0 + wn + l15) * KP1 + lhi * 8;
    auto loadB = [&](int k0, bf16x8 (&bg)[4]) { // 4 vm-instrs per wave
        #pragma unroll
        for (int j = 0; j < 4; ++j)
            bg[j] = *(const bf16x8*)(bRow + (size_t)(j * 16) * KP1 + k0);
    };

    constexpr int nk = KP1 / 32;   // 10
    f32x4 acc[4][4] = {};
    bf16x8 bgA[4], bgB[4];
    loadB(0, bgA);
    stageA(0, regA);
    asm volatile("s_waitcnt vmcnt(0)" ::: "memory");
    __syncthreads();

    auto body = [&](int k, bf16x8 (&bgu)[4], bf16x8 (&bgl)[4]) {
        RAW_BARRIER();                                   // #1: bufA[(k+1)&1] free
        if (k + 1 < nk) {
            loadB((k + 1) << 5, bgl);
            stageA((k + 1) << 5, regA + ((k + 1) & 1) * 8192);
            // queue: B(k)4,A(k)2,B(k+1)4,A(k+1)2 -> keep 6 = drain B(k)+A(k)
            asm volatile("s_waitcnt vmcnt(6)" ::: "memory");
        } else {
            asm volatile("s_waitcnt vmcnt(0)" ::: "memory");
        }
        RAW_BARRIER();                                   // #2: visibility

        __bf16* As = (__bf16*)(regA + (k & 1) * 8192);
        bf16x8 af[4];
        #pragma unroll
        for (int i = 0; i < 4; ++i)
            af[i] = *(bf16x8*)(As + (wm + i * 16 + l15) * 32 + co);
        #pragma unroll
        for (int i = 0; i < 4; ++i)
            #pragma unroll
            for (int j = 0; j < 4; ++j)
                acc[i][j] = __builtin_amdgcn_mfma_f32_16x16x32_bf16(
                    af[i], bgu[j], acc[i][j], 0, 0, 0);
    };
    for (int k = 0; k < nk; k += 2) {
        body(k, bgA, bgB);
        if (k + 1 < nk) body(k + 1, bgB, bgA);
    }
    __syncthreads();   // full drain before epilogue stores

    #pragma unroll
    for (int i = 0; i < 4; ++i)
        #pragma unroll
        for (int j = 0; j < 4; ++j) {
            int col = n0 + wn + j * 16 + l15;
            if (col < FP) {
                float bv = (col < 600) ? bias[col] : 0.f;
                #pragma unroll
                for (int e = 0; e < 4; ++e) {
                    int row = m0 + wm + i * 16 + lhi * 4 + e;
                    float v = fmaxf(acc[i][j][e] + bv, 0.f);
                    X1[(size_t)row * FP + col] = __float2bfloat16(v);
                }
            }
        }
}

// ===========================================================================
// conv2+conv3+pool fused (+ hidden t2 via noinline guest).  Writes only Y.
// A-only LDS double-buffer (2x8KB); register-B double-buffer; 2-barrier
// counted vmcnt(6).  Last iter queues Pm BEHIND the in-flight stage ->
// vmcnt(4) drains B(18)+A(18) (+1 Pm for waves 0-1, harmless); Pm fully
// drained at post-loop __syncthreads.  Ts overlays [0,17408); Pm at
// [17408,35840) (PMS=72, conflict-free).  + s_q 512B -> 36352B, 4 blocks/CU.
// ===========================================================================
__global__ __launch_bounds__(256, 4) void conv_fused_q(
    const bf16* __restrict__ A, int lda, int K,
    const bf16* __restrict__ Bt, int ldb,
    const bf16* __restrict__ Pmg,
    const float* __restrict__ bias,
    const float* __restrict__ qv,
    bf16* __restrict__ Y,
    const bf16* __restrict__ gA, int glda,
    const bf16* __restrict__ gBt, int gldb,
    const float* __restrict__ gbias,
    bf16* __restrict__ gC, int gldc, int gNcap, int gK, int gnt)
{
    __shared__ __align__(16) char regA[35840];
    __shared__ float s_q[128];

    const int tid = threadIdx.x;
    const int bid = blockIdx.x;

    if (bid >= NCONV) {
        guest_g64(gA, glda, gBt, gldb, gbias, gC, gldc, gNcap, gK, gnt,
                  bid - NCONV, regA, tid);
        return;
    }

    __bf16* Ts = (__bf16*)regA;
    __bf16* Pm = (__bf16*)(regA + 17408);

    const int lane = tid & 63;
    const int w    = tid >> 6;
    const int wm   = (w & 1) * 64;
    const int wn   = (w >> 1) * 64;
    const int l15  = lane & 15;
    const int lhi  = lane >> 4;
    const int co   = (lhi ^ ((l15 >> 1) & 3)) << 3;

    const int lid = bid >> 3;
    const int mt  = (bid & 7) * 64 + lid / 5;
    const int nt  = lid % 5;
    const int m0  = mt * 128;
    const int n0  = nt * 128;

    if (tid < 128) s_q[tid] = qv[mt * 128 + tid];   // drained by prologue vmcnt(0)

    auto stageA = [&](int k0, char* buf) {      // 2 vm-instrs per wave
        #pragma unroll
        for (int t = 0; t < 2; ++t) {
            int ci  = t * 256 + tid;
            int row = ci >> 2;
            int kc  = (ci & 3) ^ ((row >> 1) & 3);
            llds16(A + (size_t)(m0 + row) * lda + k0 + kc * 8,
                   buf + (size_t)(t * 256 + w * 64) * 16);
        }
    };
    const bf16* bRow = Bt + (size_t)(n0 + wn + l15) * ldb + lhi * 8;
    auto loadB = [&](int k0, bf16x8 (&bg)[4]) { // 4 vm-instrs per wave
        #pragma unroll
        for (int j = 0; j < 4; ++j)
            bg[j] = *(const bf16x8*)(bRow + (size_t)(j * 16) * ldb + k0);
    };

    const int nk = K >> 5;     // 19
    f32x4 acc[4][4] = {};
    bf16x8 bgA[4], bgB[4];
    loadB(0, bgA);
    stageA(0, regA);
    asm volatile("s_waitcnt vmcnt(0)" ::: "memory");
    __syncthreads();

    auto body = [&](int k, bf16x8 (&bgu)[4], bf16x8 (&bgl)[4]) {
        RAW_BARRIER();                                   // #1
        if (k + 1 < nk) {
            loadB((k + 1) << 5, bgl);
            stageA((k + 1) << 5, regA + ((k + 1) & 1) * 8192);
            asm volatile("s_waitcnt vmcnt(6)" ::: "memory"); // drains B(k)+A(k)
        } else {
            // Pm stage into [17408, 35840): 1152 chunks (4x256 + 128),
            // queued BEHIND B(k)+A(k) so vmcnt(4) drains them exactly.
            #pragma unroll
            for (int i = 0; i < 4; ++i)
                llds16(Pmg + (size_t)mt * (128 * PMS) + (size_t)(i * 256 + tid) * 8,
                       (char*)Pm + (size_t)(i * 256 + w * 64) * 16);
            if (w < 2)
                llds16(Pmg + (size_t)mt * (128 * PMS) + (size_t)(1024 + w * 64 + lane) * 8,
                       (char*)Pm + (size_t)(1024 + w * 64) * 16);
            asm volatile("s_waitcnt vmcnt(4)" ::: "memory");
        }
        RAW_BARRIER();                                   // #2

        __bf16* As = (__bf16*)(regA + (k & 1) * 8192);
        bf16x8 af[4];
        #pragma unroll
        for (int i = 0; i < 4; ++i)
            af[i] = *(bf16x8*)(As + (wm + i * 16 + l15) * 32 + co);
        #pragma unroll
        for (int i = 0; i < 4; ++i)
            #pragma unroll
            for (int j = 0; j < 4; ++j)
                acc[i][j] = __builtin_amdgcn_mfma_f32_16x16x32_bf16(
                    af[i], bgu[j], acc[i][j], 0, 0, 0);
    };
    for (int k = 0; k < nk; k += 2) {
        body(k, bgA, bgB);
        if (k + 1 < nk) body(k + 1, bgB, bgA);
    }
    __syncthreads();   // full drain: Pm landed, all compute done, Ts overlay safe

    const int g  = w & 1;
    const int nb = w >> 1;
    #pragma unroll
    for (int h = 0; h < 2; ++h) {
        if (wn == h * 64) {
            #pragma unroll
            for (int i = 0; i < 4; ++i)
                #pragma unroll
                for (int j = 0; j < 4; ++j) {
                    int c_local = j * 16 + l15;
                    int rbase   = wm + i * 16 + lhi * 4;
                    bf16x4 pk;
                    #pragma unroll
                    for (int e = 0; e < 4; ++e) pk[e] = (__bf16)acc[i][j][e];
                    *(bf16x4*)(Ts + c_local * 136 + rbase) = pk;
                }
        }
        __syncthreads();

        f32x4 acc2[4][2] = {};
        #pragma unroll
        for (int k0 = 0; k0 < 64; k0 += 32) {
            bf16x8 pa[4], hb[2];
            #pragma unroll
            for (int i = 0; i < 4; ++i)
                pa[i] = *(bf16x8*)(Pm + (g * 64 + i * 16 + l15) * PMS + k0 + lhi * 8);
            #pragma unroll
            for (int j = 0; j < 2; ++j)
                hb[j] = *(bf16x8*)(Ts + (nb * 32 + j * 16 + l15) * 136
                                      + g * 64 + k0 + lhi * 8);
            #pragma unroll
            for (int i = 0; i < 4; ++i)
                #pragma unroll
                for (int j = 0; j < 2; ++j)
                    acc2[i][j] = __builtin_amdgcn_mfma_f32_16x16x32_bf16(
                        pa[i], hb[j], acc2[i][j], 0, 0, 0);
        }
        #pragma unroll
        for (int j = 0; j < 2; ++j) {
            int col = n0 + h * 64 + nb * 32 + j * 16 + l15;
            float bv = (col < 600) ? bias[col] : 0.f;
            float yp = 0.f;
            #pragma unroll
            for (int i = 0; i < 4; ++i)
                #pragma unroll
                for (int e = 0; e < 4; ++e) {
                    float v = fmaxf(acc2[i][j][e] + bv, 0.f);   // relu
                    yp += s_q[g * 64 + i * 16 + lhi * 4 + e] * v;
                }
            yp += __shfl_xor(yp, 16, 64);
            yp += __shfl_xor(yp, 32, 64);
            if (lhi == 0 && col < FP)
                Y[(size_t)(mt * 2 + g) * FP + col] = __float2bfloat16(yp);
        }
        __syncthreads();
    }
}

// ===========================================================================
// Mega prep: [WT transposes | timestep emb | pair prep (Pmg,qv) | PX0 branch]
// ===========================================================================
struct WtJob  { const float* src; bf16* dst; int Ksrc, Nsrc, Kp, Np, blk0; };
struct PrepArgs {
    WtJob j[9];
    int nwt, te0, pp0, xtr0;
    const int*   ei;
    const float* ts;
    const float* xin; const float* Wtr; const float* btr; const float* mask;
    bf16* TE; bf16* Pmg; float* qv; bf16* PX0;
};

__global__ __launch_bounds__(256) void k_prep(PrepArgs a)
{
    __shared__ __align__(16) char sm[35840];
    const int bx  = blockIdx.x;
    const int tid = threadIdx.x;

    if (bx < a.nwt) {
        int ji = 0;
        while (ji < 8 && bx >= a.j[ji + 1].blk0) ++ji;
        WtJob jb = a.j[ji];
        int t  = bx - jb.blk0;
        int kt = (jb.Kp + 63) >> 6;
        int ti = t % kt, tj = t / kt;
        int kg0 = ti * 64, ng0 = tj * 64;
        float (*T)[65] = (float(*)[65])sm;
        #pragma unroll 4
        for (int r = 0; r < 16; ++r) {
            int kl = (tid >> 6) + r * 4, nl = tid & 63;
            int kg = kg0 + kl, ng = ng0 + nl;
            T[kl][nl] = (kg < jb.Ksrc && ng < jb.Nsrc)
                        ? jb.src[(size_t)kg * jb.Nsrc + ng] : 0.f;
        }
        __syncthreads();
        #pragma unroll 4
        for (int r = 0; r < 16; ++r) {
            int nl = (tid >> 6) + r * 4, kl = tid & 63;
            int ng = ng0 + nl, kg = kg0 + kl;
            if (ng < jb.Np && kg < jb.Kp)
                jb.dst[(size_t)ng * jb.Kp + kg] = __float2bfloat16(T[kl][nl]);
        }
    } else if (bx < a.pp0) {
        int idx = (bx - a.te0) * 256 + tid;
        int b = idx >> 7, jj = idx & 127;
        float tt = a.ts[b];
        int h = jj & 63;
        float freq = expf(-9.210340371976184f * (float)h / 64.f);  // ln(10000)
        float ang = tt * freq;
        a.TE[idx] = __float2bfloat16((jj < 64) ? cosf(ang) : sinf(ang));
    } else if (bx < a.xtr0) {
        // ---------- pair prep: P matrix (bf16, PMS stride) + q vector ----------
        int pr = bx - a.pp0;
        float* Pf   = (float*)sm;
        int*   cnt  = (int*)(sm + 32768);
        float* sQ   = (float*)(sm + 33280);
        float* sI   = (float*)(sm + 33792);
        float* sIvd = (float*)(sm + 34304);

        for (int idx = tid; idx < 8192; idx += 256) Pf[idx] = 0.f;
        if (tid < 128) cnt[tid] = 0;
        __syncthreads();
        for (int e = tid; e < 2 * EPG; e += 256) {
            int g  = (e >= EPG);
            int eg = (2 * pr + g) * EPG + (e - g * EPG);
            int ld = (a.ei[E + eg] & 63) + g * 64;
            atomicAdd(&cnt[ld], 1);
        }
        __syncthreads();
        if (tid < 128) {
            float d = (float)cnt[tid] + 1.0f;
            float iv = 1.f / d;
            sIvd[tid] = iv;
            sI[tid]   = rsqrtf(d);
            sQ[tid]   = iv;
        }
        __syncthreads();
        for (int e = tid; e < 2 * EPG; e += 256) {
            int g   = (e >= EPG);
            int eg  = (2 * pr + g) * EPG + (e - g * EPG);
            int lsl = a.ei[eg] & 63;
            int ldl = a.ei[E + eg] & 63;
            float cf = sI[g * 64 + lsl] * sI[g * 64 + ldl];
            atomicAdd(&Pf[(g * 64 + ldl) * 64 + lsl], cf);
            atomicAdd(&sQ[g * 64 + lsl], cf);
        }
        __syncthreads();
        if (tid < 128) {
            Pf[tid * 64 + (tid & 63)] += sIvd[tid];
            a.qv[pr * 128 + tid] = sQ[tid] * (1.f / 64.f);
        }
        __syncthreads();
        for (int idx = tid; idx < 128 * PMS; idx += 256) {
            int r = idx / PMS, k = idx - r * PMS;
            float v = (k < 64) ? Pf[r * 64 + k] : 0.f;
            a.Pmg[(size_t)pr * (128 * PMS) + idx] = __float2bfloat16(v);
        }
    } else {
        // ---------- PX0 branch (per graph) ----------
        int g = bx - a.xtr0;
        float* Pf  = (float*)sm;                 // 64*64 fp32 [0,16384); Ws overlays later
        float* Ws  = (float*)sm;                 // 19*304 fp32 [0,23104)
        float* xm  = (float*)(sm + 23104);       // 64*20 (col 19 = mask)
        float* xa  = (float*)(sm + 28224);       // 64*20 (col 19 = ba)
        float* isqv= (float*)(sm + 33344);       // 64
        float* ivdv= (float*)(sm + 33600);       // 64
        int*   cnt = (int*)  (sm + 33856);       // 64
        float* sb  = (float*)(sm + 34112);       // 304 fp32 -> ends 35328

        for (int idx = tid; idx < 4096; idx += 256) Pf[idx] = 0.f;
        if (tid < 64) cnt[tid] = 0;
        __syncthreads();
        for (int e = tid; e < EPG; e += 256)
            atomicAdd(&cnt[a.ei[E + g * EPG + e] & 63], 1);
        __syncthreads();
        if (tid < 64) {
            float d = (float)cnt[tid] + 1.0f;
            ivdv[tid] = 1.f / d;
            isqv[tid] = rsqrtf(d);
        }
        __syncthreads();
        for (int e = tid; e < EPG; e += 256) {
            int ls = a.ei[g * EPG + e] & 63;
            int ld = a.ei[E + g * EPG + e] & 63;
            atomicAdd(&Pf[ld * 64 + ls], isqv[ls] * isqv[ld]);
        }
        // xm load (independent of P)
        for (int idx = tid; idx < 64 * 20; idx += 256) {
            int n = idx / 20, j = idx - n * 20;
            float mv = a.mask[g * 64 + n];
            xm[idx] = (j < 19) ? mv * a.xin[(size_t)(g * 64 + n) * 19 + j] : mv;
        }
        __syncthreads();
        if (tid < 64) Pf[tid * 64 + tid] += ivdv[tid];
        __syncthreads();
        // xa[r][j] = sum_s Pf[r][s] * xm[s][j]  (j=19 gives ba)
        for (int idx = tid; idx < 64 * 20; idx += 256) {
            int r = idx / 20, j = idx - r * 20;
            float s = 0.f;
            #pragma unroll 8
            for (int s2 = 0; s2 < 64; ++s2)
                s += Pf[r * 64 + s2] * xm[s2 * 20 + j];
            xa[idx] = s;
        }
        __syncthreads();
        // Ws/sb load (Pf dead)
        for (int idx = tid; idx < 19 * 304; idx += 256) {
            int k = idx / 304, c = idx - k * 304;
            Ws[idx] = (c < 300) ? a.Wtr[k * 300 + c] : 0.f;
        }
        for (int c = tid; c < 304; c += 256)
            sb[c] = (c < 300) ? a.btr[c] : 0.f;
        __syncthreads();
        // PX0[r][c] = sum_j xa[r][j]*Ws[j][c] + ba[r]*sb[c]
        int n  = tid >> 2;
        int c0 = tid & 3;
        float ba = xa[n * 20 + 19];
        for (int c = c0; c < 304; c += 4) {
            float acc = ba * sb[c];
            #pragma unroll
            for (int k = 0; k < 19; ++k)
                acc += xa[n * 20 + k] * Ws[k * 304 + c];
            a.PX0[(size_t)(g * 64 + n) * KP1 + c] = __float2bfloat16(acc);
        }
        // zero cols 304..319
        bf16x8 z = {};
        for (int idx = tid; idx < 64 * 2; idx += 256) {
            int nn = idx >> 1, jv = idx & 1;
            *(bf16x8*)((__bf16*)a.PX0 + (size_t)(g * 64 + nn) * KP1 + 304 + jv * 8) = z;
        }
    }
}

// LayerNorm over 300 dims + affine, fp32 out; fused text passthrough copy
__global__ __launch_bounds__(256) void k_ln_copy(const float* __restrict__ G,
                                                 const float* __restrict__ lg,
                                                 const float* __restrict__ lb,
                                                 const float* __restrict__ text,
                                                 float* __restrict__ out)
{
    int r = blockIdx.x;
    int tid = threadIdx.x;
    __shared__ float red[4];
    __shared__ float smu, svar;

    float v0 = (tid < 300) ? G[r * 300 + tid] : 0.f;
    float v1 = (tid + 256 < 300) ? G[r * 300 + tid + 256] : 0.f;
    float s = v0 + v1;
    #pragma unroll
    for (int o = 32; o > 0; o >>= 1) s += __shfl_down(s, o, 64);
    if ((tid & 63) == 0) red[tid >> 6] = s;
    __syncthreads();
    if (tid == 0) smu = (red[0] + red[1] + red[2] + red[3]) * (1.f / 300.f);
    __syncthreads();
    float mu = smu;
    float d0 = (tid < 300) ? v0 - mu : 0.f;
    float d1 = (tid + 256 < 300) ? v1 - mu : 0.f;
    s = d0 * d0 + d1 * d1;
    #pragma unroll
    for (int o = 32; o > 0; o >>= 1) s += __shfl_down(s, o, 64);
    if ((tid & 63) == 0) red[tid >> 6] = s;
    __syncthreads();
    if (tid == 0) svar = (red[0] + red[1] + red[2] + red[3]) * (1.f / 300.f);
    __syncthreads();
    float rstd = rsqrtf(svar + 1e-5f);
    if (tid < 300)
        out[r * 300 + tid] = d0 * rstd * lg[tid] + lb[tid];
    if (tid + 256 < 300)
        out[r * 300 + tid + 256] = d1 * rstd * lg[tid + 256] + lb[tid + 256];
    float* o2 = out + (size_t)B * 300;
    for (int c = tid; c < 300; c += 256)
        o2[(size_t)r * 300 + c] = text[(size_t)r * 300 + c];
}

// ---------------------------------------------------------------------------
extern "C" void kernel_launch(void* const* d_in, const int* in_sizes, int n_in,
                              void* d_out, int out_size, void* d_ws, size_t ws_size,
                              hipStream_t stream)
{
    const float* x_in  = (const float*)d_in[0];
    const int*   ei    = (const int*)d_in[1];
    const float* text  = (const float*)d_in[3];
    const float* tst   = (const float*)d_in[4];
    const float* mask  = (const float*)d_in[5];
    const float* W_tr  = (const float*)d_in[6];
    const float* b_tr  = (const float*)d_in[7];
    const float* W_c1  = (const float*)d_in[8];
    const float* b_c1  = (const float*)d_in[9];
    const float* W_c2  = (const float*)d_in[10];
    const float* b_c2  = (const float*)d_in[11];
    const float* W_c3  = (const float*)d_in[12];
    const float* b_c3  = (const float*)d_in[13];
    const float* W_h1  = (const float*)d_in[14];
    const float* b_h1  = (const float*)d_in[15];
    const float* W_h2  = (const float*)d_in[16];
    const float* b_h2  = (const float*)d_in[17];
    const float* W_h3  = (const float*)d_in[18];
    const float* b_h3  = (const float*)d_in[19];
    const float* ln_g  = (const float*)d_in[20];
    const float* ln_b  = (const float*)d_in[21];
    const float* W_t1  = (const float*)d_in[22];
    const float* b_t1  = (const float*)d_in[23];
    const float* W_t2  = (const float*)d_in[24];
    const float* b_t2  = (const float*)d_in[25];
    const float* W_e   = (const float*)d_in[26];
    const float* b_e   = (const float*)d_in[27];

    // workspace carve (256B aligned) — ~150 MB
    char* w = (char*)d_ws;
    size_t off = 0;
    auto carve = [&](size_t bytes) {
        void* p = w + off;
        off += (bytes + 255) & ~(size_t)255;
        return p;
    };
    bf16*  PX0    = (bf16*) carve((size_t)BN * KP1 * 2);     // 42 MB
    bf16*  X1     = (bf16*) carve((size_t)BN * FP * 2);      // 79.7 MB
    bf16*  Wb1    = (bf16*) carve((size_t)640 * KP1 * 2);
    bf16*  Wb2    = (bf16*) carve((size_t)640 * FP * 2);
    bf16*  Wb3    = (bf16*) carve((size_t)640 * FP * 2);
    bf16*  Wt1t   = (bf16*) carve((size_t)512 * 128 * 2);
    bf16*  Wt2t   = (bf16*) carve((size_t)512 * 512 * 2);
    bf16*  Wet    = (bf16*) carve((size_t)3072 * 512 * 2);
    bf16*  Wh1t   = (bf16*) carve((size_t)640 * FP * 2);
    bf16*  Wh2t   = (bf16*) carve((size_t)640 * FP * 2);
    bf16*  Wh3t   = (bf16*) carve((size_t)384 * FP * 2);
    bf16*  TE     = (bf16*) carve((size_t)B * 128 * 2);
    bf16*  A1b    = (bf16*) carve((size_t)B * 512 * 2);
    bf16*  A2b    = (bf16*) carve((size_t)B * 512 * 2);
    bf16*  EO     = (bf16*) carve((size_t)B * 3000 * 2);
    bf16*  Yv     = (bf16*) carve((size_t)B * FP * 2);
    bf16*  G0     = (bf16*) carve((size_t)B * FP * 2);
    bf16*  G1     = (bf16*) carve((size_t)B * FP * 2);
    bf16*  G2     = (bf16*) carve((size_t)B * FP * 2);
    float* G3     = (float*)carve((size_t)B * 300 * 4);
    bf16*  Pmg    = (bf16*) carve((size_t)512 * 128 * PMS * 2);  // 9.4 MB
    float* qv     = (float*)carve((size_t)BN * 4);
    (void)ws_size; (void)in_sizes; (void)n_in; (void)out_size;

    float* out = (float*)d_out;

    // --- phase A: one mega prep launch ---
    PrepArgs pa;
    struct JD { const float* s; bf16* d; int Ks, Ns, Kp, Np; };
    JD jd[9] = {
        { W_c1, Wb1,  300, 600,  KP1, 640 },
        { W_c2, Wb2,  600, 600,  FP,  640 },
        { W_c3, Wb3,  600, 600,  FP,  640 },
        { W_t1, Wt1t, 128, 512,  128, 512 },
        { W_t2, Wt2t, 512, 512,  512, 512 },
        { W_e,  Wet,  512, 3000, 512, 3072 },
        { W_h1, Wh1t, 600, 600,  FP,  640 },
        { W_h2, Wh2t, 600, 600,  FP,  640 },
        { W_h3, Wh3t, 600, 300,  FP,  384 },
    };
    int cum = 0;
    for (int i = 0; i < 9; ++i) {
        int kt = (jd[i].Kp + 63) >> 6, nt = (jd[i].Np + 63) >> 6;
        pa.j[i] = { jd[i].s, jd[i].d, jd[i].Ks, jd[i].Ns, jd[i].Kp, jd[i].Np, cum };
        cum += kt * nt;
    }
    pa.nwt  = cum;
    pa.te0  = cum;       cum += (B * 128) / 256;
    pa.pp0  = cum;       cum += B / 2;
    pa.xtr0 = cum;       cum += B;
    pa.ei = ei; pa.ts = tst;
    pa.xin = x_in; pa.Wtr = W_tr; pa.btr = b_tr; pa.mask = mask;
    pa.TE = TE; pa.Pmg = Pmg; pa.qv = qv; pa.PX0 = PX0;
    k_prep<<<cum, 256, 0, stream>>>(pa);

    // --- conv1 as plain GEMM (+hidden t1: A1b = relu(TE @ Wt1t^T + b_t1)) ---
    conv1_gemm<<<NCONV + 64, 256, 0, stream>>>(
        PX0, Wb1, b_c1, X1,
        TE, 128, Wt1t, 128, b_t1, A1b, 512, 512, 128, 4);

    // --- conv2+conv3+pool (+hidden t2: A2b = relu(A1b @ Wt2t^T + b_t2)) ---
    conv_fused_q<<<NCONV + 64, 256, 0, stream>>>(
        X1, FP, FP, Wb2, FP, Pmg, b_c2, qv, Yv,
        A1b, 512, Wt2t, 512, b_t2, A2b, 512, 512, 512, 4);

    // --- EO = A2b @ Wet^T + b_e (384 blocks) || G0 = Yv @ Wb3^T + b_c3 (80) ---
    k_two_gemms<<<464, 256, 0, stream>>>(A2b, Wet, b_e, EO, Yv, Wb3, b_c3, G0);

    // --- h-layers with FiLM (64-row tiles) ---
    gemm64<true, true, bf16><<<dim3(16, 5), 256, 0, stream>>>(
        G0, FP, Wh1t, FP, b_h1, G1, FP, 600, EO + 0, EO + 600, 3000, FP);
    gemm64<true, true, bf16><<<dim3(16, 5), 256, 0, stream>>>(
        G1, FP, Wh2t, FP, b_h2, G2, FP, 600, EO + 1200, EO + 1800, 3000, FP);
    gemm64<false, true, float><<<dim3(16, 3), 256, 0, stream>>>(
        G2, FP, Wh3t, FP, b_h3, G3, 300, 300, EO + 2400, EO + 2700, 3000, FP);

    // --- layer norm + text passthrough ---
    k_ln_copy<<<B, 256, 0, stream>>>(G3, ln_g, ln_b, text, out);
}

// Round 13
// 331.913 us; speedup vs baseline: 1.2405x; 1.2405x over previous
//
#include <hip/hip_runtime.h>
#include <hip/hip_bf16.h>
#include <cstdint>
#include <cstddef>

// Problem constants
static constexpr int B   = 1024;
static constexpr int N   = 64;
static constexpr int BN  = B * N;      // 65536 nodes
static constexpr int EPG = 192;
static constexpr int E   = B * EPG;    // 196608 edges
static constexpr int FP  = 608;        // padded feature dim (mult of 32)
static constexpr int KP1 = 320;        // conv1 K (PX0 cols, padded)
static constexpr int PMS = 72;         // Pm row stride (bf16): 144B -> conflict-free
static constexpr int NCONV = 2560;     // conv blocks per conv dispatch

typedef __hip_bfloat16 bf16;
typedef __bf16 bf16x8 __attribute__((ext_vector_type(8)));
typedef __bf16 bf16x4 __attribute__((ext_vector_type(4)));
typedef float  f32x4  __attribute__((ext_vector_type(4)));

__device__ __forceinline__ void storeC(float* p, float v) { *p = v; }
__device__ __forceinline__ void storeC(bf16* p, float v) { *p = __float2bfloat16(v); }

// async global->LDS, 16B per lane; LDS dest is wave-uniform base + lane*16
__device__ __forceinline__ void llds16(const void* g, void* l) {
    __builtin_amdgcn_global_load_lds(
        (const __attribute__((address_space(1))) unsigned int*)g,
        (__attribute__((address_space(3))) unsigned int*)l,
        16, 0, 0);
}

#define RAW_BARRIER() do { __builtin_amdgcn_s_barrier(); \
                           asm volatile("" ::: "memory"); } while (0)

// ===========================================================================
// Counted-vmcnt double-buffer schedule (R11-proven, session best 334.2us):
//   iter k (k+1 < nk):
//     bar#1   [all waves done READING buf[(k+1)&1] (they read it in k-1)]
//     issue stage(k+1) -> buf[(k+1)&1]
//     vmcnt(S)  [queue = stage(k)+stage(k+1) = 2S -> drains exactly stage(k);
//                stage(k+1) stays in flight a FULL iteration]
//     bar#2   [all waves' stage(k) visible]
//     ds_read buf[k&1] + MFMA
//   iter nk-1: NO new stage -> vmcnt(0) (g64/conv1); conv_fused queues Pm
//     BEHIND stage(nk-1) so vmcnt(4) is exact there.
// LDS tile swizzle (BK=32, 64B rows): slot(row,s) holds chunk s^((row>>1)&3);
// read offset co = (lhi ^ ((l15>>1)&3))*8 elems -> conflict-free b128 reads.
// Session ceiling note: conv_fused_q is LDS-BW-bound at ~48KB LDS traffic
// per block-iter (~250cy model = 246cy measured); occupancy (R7), global
// traffic (R8), prefetch depth (R4), register-B (R4/R12: spills) all null
// or negative.  This structure is the verified optimum of the family.
// ===========================================================================

// ---------------------------------------------------------------------------
// 4-wave 64x128 tile body (256 threads).  lds: buf0 [0,12K), buf1 [12K,24K).
// Stage = 3 vm-instructions/wave -> vmcnt(3).
// ---------------------------------------------------------------------------
template<bool RELU, bool FILM, typename CT>
__device__ __forceinline__ void g64_tile(
    const bf16* __restrict__ A, int lda,
    const bf16* __restrict__ Bt, int ldb,
    const float* __restrict__ bias,
    CT* __restrict__ C, int ldc, int Ncap,
    const bf16* __restrict__ fS, const bf16* __restrict__ fT, int fstride,
    int K, int m0, int n0, char* lds, int tid)
{
    const int lane = tid & 63;
    const int w    = tid >> 6;
    const int wn   = w * 32;
    const int l15  = lane & 15;
    const int lhi  = lane >> 4;
    const int co   = (lhi ^ ((l15 >> 1) & 3)) << 3;
    const int nk   = K >> 5;

    auto stage = [&](int k0, char* buf) {
        {   // A tile: 64 rows x 4 chunks = 256
            int row = tid >> 2;
            int kc  = (tid & 3) ^ ((row >> 1) & 3);
            llds16(A + (size_t)(m0 + row) * lda + k0 + kc * 8,
                   buf + (size_t)(w * 64) * 16);
        }
        #pragma unroll
        for (int t = 0; t < 2; ++t) {   // B tile: 128 rows = 512 chunks
            int ci  = t * 256 + tid;
            int row = ci >> 2;
            int kc  = (ci & 3) ^ ((row >> 1) & 3);
            llds16(Bt + (size_t)(n0 + row) * ldb + k0 + kc * 8,
                   buf + 4096 + (size_t)(t * 256 + w * 64) * 16);
        }
    };

    f32x4 acc[4][2] = {};
    stage(0, lds);
    asm volatile("s_waitcnt vmcnt(0)" ::: "memory");
    __syncthreads();

    for (int k = 0; k < nk; ++k) {
        RAW_BARRIER();                                   // #1: buf[(k+1)&1] free
        if (k + 1 < nk) {
            stage((k + 1) << 5, lds + ((k + 1) & 1) * 12288);
            asm volatile("s_waitcnt vmcnt(3)" ::: "memory"); // drains stage(k)
        } else {
            asm volatile("s_waitcnt vmcnt(0)" ::: "memory"); // last tile landed
        }
        RAW_BARRIER();                                   // #2: visibility

        __bf16* As = (__bf16*)(lds + (k & 1) * 12288);
        __bf16* Bs = As + 2048;
        bf16x8 af[4], bg[2];
        #pragma unroll
        for (int i = 0; i < 4; ++i)
            af[i] = *(bf16x8*)(As + (i * 16 + l15) * 32 + co);
        #pragma unroll
        for (int j = 0; j < 2; ++j)
            bg[j] = *(bf16x8*)(Bs + (wn + j * 16 + l15) * 32 + co);
        #pragma unroll
        for (int i = 0; i < 4; ++i)
            #pragma unroll
            for (int j = 0; j < 2; ++j)
                acc[i][j] = __builtin_amdgcn_mfma_f32_16x16x32_bf16(
                    af[i], bg[j], acc[i][j], 0, 0, 0);
    }
    __syncthreads();   // full drain before epilogue

    #pragma unroll
    for (int i = 0; i < 4; ++i) {
        #pragma unroll
        for (int j = 0; j < 2; ++j) {
            int col = n0 + wn + j * 16 + l15;
            if (col < Ncap) {
                float bv = bias ? bias[col] : 0.f;
                #pragma unroll
                for (int e = 0; e < 4; ++e) {
                    int row = m0 + i * 16 + lhi * 4 + e;
                    float v = acc[i][j][e] + bv;
                    if (RELU) v = fmaxf(v, 0.f);
                    if (FILM) {
                        float sv = __bfloat162float(fS[(size_t)row * fstride + col]);
                        float tv = __bfloat162float(fT[(size_t)row * fstride + col]);
                        v = v * (1.f + sv) + tv;
                    }
                    storeC(&C[(size_t)row * ldc + col], v);
                }
            }
        }
    }
}

// noinline guest wrapper: keeps guest register usage from inflating the host
// conv kernel's VGPR allocation.  Needs 24KB of lds.
__device__ __attribute__((noinline)) void guest_g64(
    const bf16* gA, int glda, const bf16* gBt, int gldb,
    const float* gbias, bf16* gC, int gldc, int gNcap, int gK, int gnt,
    int t, char* lds, int tid)
{
    int mt2 = t / gnt, nt2 = t % gnt;
    g64_tile<true, false, bf16>(gA, glda, gBt, gldb, gbias, gC, gldc, gNcap,
                                nullptr, nullptr, 0, gK, mt2 * 64, nt2 * 128,
                                lds, tid);
}

// standalone 64-row-tile GEMM (h-layers)
template<bool RELU, bool FILM, typename CT>
__global__ __launch_bounds__(256) void gemm64(
    const bf16* __restrict__ A, int lda,
    const bf16* __restrict__ Bt, int ldb,
    const float* __restrict__ bias,
    CT* __restrict__ C, int ldc, int Ncap,
    const bf16* __restrict__ fS, const bf16* __restrict__ fT, int fstride,
    int K)
{
    __shared__ __align__(16) char lds[24576];
    g64_tile<RELU, FILM, CT>(A, lda, Bt, ldb, bias, C, ldc, Ncap,
                             fS, fT, fstride, K,
                             blockIdx.x * 64, blockIdx.y * 128, lds,
                             threadIdx.x);
}

// two independent small GEMMs in one dispatch: EO (384 blocks) + W3 (80)
__global__ __launch_bounds__(256) void k_two_gemms(
    const bf16* __restrict__ A2b, const bf16* __restrict__ Wet,
    const float* __restrict__ b_e, bf16* __restrict__ EO,
    const bf16* __restrict__ Yv, const bf16* __restrict__ Wb3,
    const float* __restrict__ b_c3, bf16* __restrict__ G0)
{
    __shared__ __align__(16) char lds[24576];
    int bid = blockIdx.x;
    if (bid < 384) {
        int mt = bid / 24, nt = bid % 24;
        g64_tile<false, false, bf16>(A2b, 512, Wet, 512, b_e, EO, 3000, 3000,
                                     nullptr, nullptr, 0, 512,
                                     mt * 64, nt * 128, lds, threadIdx.x);
    } else {
        int t = bid - 384;
        int mt = t / 5, nt = t % 5;
        g64_tile<false, false, bf16>(Yv, FP, Wb3, FP, b_c3, G0, FP, 600,
                                     nullptr, nullptr, 0, FP,
                                     mt * 64, nt * 128, lds, threadIdx.x);
    }
}

// ===========================================================================
// conv1 as a PLAIN GEMM (aggregation pre-commuted into PX0):
// X1 = relu(PX0 @ Wb1^T + b_c1).  128x128 tiles, BK=32, double-buffered with
// the 2-barrier counted-vmcnt(4) schedule (+ last-iter vmcnt(0)),
// XCD-swizzled. + hidden t1 guest.
// lds: buf0 [0,16K) = As0[0,8K) Bs0[8K,16K); buf1 [16K,32K).
// ===========================================================================
__global__ __launch_bounds__(256, 4) void conv1_gemm(
    const bf16* __restrict__ A,        // PX0, lda = KP1
    const bf16* __restrict__ Bt,       // Wb1, ldb = KP1
    const float* __restrict__ bias,
    bf16* __restrict__ X1,
    const bf16* __restrict__ gA, int glda,
    const bf16* __restrict__ gBt, int gldb,
    const float* __restrict__ gbias,
    bf16* __restrict__ gC, int gldc, int gNcap, int gK, int gnt)
{
    __shared__ __align__(16) char regA[32768];
    const int tid = threadIdx.x;
    const int bid = blockIdx.x;

    if (bid >= NCONV) {
        guest_g64(gA, glda, gBt, gldb, gbias, gC, gldc, gNcap, gK, gnt,
                  bid - NCONV, regA, tid);
        return;
    }

    const int lane = tid & 63;
    const int w    = tid >> 6;
    const int wm   = (w & 1) * 64;
    const int wn   = (w >> 1) * 64;
    const int l15  = lane & 15;
    const int lhi  = lane >> 4;
    const int co   = (lhi ^ ((l15 >> 1) & 3)) << 3;

    const int lid = bid >> 3;
    const int mt  = (bid & 7) * 64 + lid / 5;
    const int nt  = lid % 5;
    const int m0  = mt * 128;
    const int n0  = nt * 128;

    auto stage = [&](int k0, char* buf) {       // 4 vm-instrs per wave
        #pragma unroll
        for (int t = 0; t < 2; ++t) {
            int ci  = t * 256 + tid;
            int row = ci >> 2;
            int kc  = (ci & 3) ^ ((row >> 1) & 3);
            llds16(A  + (size_t)(m0 + row) * KP1 + k0 + kc * 8,
                   buf + (size_t)(t * 256 + w * 64) * 16);
            llds16(Bt + (size_t)(n0 + row) * KP1 + k0 + kc * 8,
                   buf + 8192 + (size_t)(t * 256 + w * 64) * 16);
        }
    };

    constexpr int nk = KP1 / 32;   // 10
    f32x4 acc[4][4] = {};
    stage(0, regA);
    asm volatile("s_waitcnt vmcnt(0)" ::: "memory");
    __syncthreads();

    for (int k = 0; k < nk; ++k) {
        RAW_BARRIER();                                   // #1
        if (k + 1 < nk) {
            stage((k + 1) << 5, regA + ((k + 1) & 1) * 16384);
            asm volatile("s_waitcnt vmcnt(4)" ::: "memory"); // drains stage(k)
        } else {
            asm volatile("s_waitcnt vmcnt(0)" ::: "memory"); // last tile landed
        }
        RAW_BARRIER();                                   // #2

        __bf16* As = (__bf16*)(regA + (k & 1) * 16384);
        __bf16* Bs = As + 4096;
        bf16x8 af[4], bg[4];
        #pragma unroll
        for (int i = 0; i < 4; ++i)
            af[i] = *(bf16x8*)(As + (wm + i * 16 + l15) * 32 + co);
        #pragma unroll
        for (int j = 0; j < 4; ++j)
            bg[j] = *(bf16x8*)(Bs + (wn + j * 16 + l15) * 32 + co);
        #pragma unroll
        for (int i = 0; i < 4; ++i)
            #pragma unroll
            for (int j = 0; j < 4; ++j)
                acc[i][j] = __builtin_amdgcn_mfma_f32_16x16x32_bf16(
                    af[i], bg[j], acc[i][j], 0, 0, 0);
    }
    __syncthreads();   // full drain before epilogue stores

    #pragma unroll
    for (int i = 0; i < 4; ++i)
        #pragma unroll
        for (int j = 0; j < 4; ++j) {
            int col = n0 + wn + j * 16 + l15;
            if (col < FP) {
                float bv = (col < 600) ? bias[col] : 0.f;
                #pragma unroll
                for (int e = 0; e < 4; ++e) {
                    int row = m0 + wm + i * 16 + lhi * 4 + e;
                    float v = fmaxf(acc[i][j][e] + bv, 0.f);
                    X1[(size_t)row * FP + col] = __float2bfloat16(v);
                }
            }
        }
}

// ===========================================================================
// conv2+conv3+pool fused (+ hidden t2 via noinline guest).  Writes only Y.
// Double-buffered BK=32 loop, 2-barrier counted-vmcnt(4) schedule.  Last iter
// queues Pm BEHIND stage(nk-1), so vmcnt(4) there drains the stage exactly
// (+1 Pm load for waves 0-1, harmless); Pm fully drained at post-loop sync.
// Pm (PMS=72, conflict-free) lives in the dead buf1 region; Ts overlays buf0.
// lds map: [0,16K) buf0 | [16K,32K) buf1 | post-loop: Ts [0,17392),
//          Pm [17408, 35840).  + s_q 512B.  Total ~36.9KB -> 4 blocks/CU.
// ===========================================================================
__global__ __launch_bounds__(256, 4) void conv_fused_q(
    const bf16* __restrict__ A, int lda, int K,
    const bf16* __restrict__ Bt, int ldb,
    const bf16* __restrict__ Pmg,
    const float* __restrict__ bias,
    const float* __restrict__ qv,
    bf16* __restrict__ Y,
    const bf16* __restrict__ gA, int glda,
    const bf16* __restrict__ gBt, int gldb,
    const float* __restrict__ gbias,
    bf16* __restrict__ gC, int gldc, int gNcap, int gK, int gnt)
{
    __shared__ __align__(16) char regA[35840];
    __shared__ float s_q[128];

    const int tid = threadIdx.x;
    const int bid = blockIdx.x;

    if (bid >= NCONV) {
        guest_g64(gA, glda, gBt, gldb, gbias, gC, gldc, gNcap, gK, gnt,
                  bid - NCONV, regA, tid);
        return;
    }

    __bf16* Ts = (__bf16*)regA;
    __bf16* Pm = (__bf16*)(regA + 17408);

    const int lane = tid & 63;
    const int w    = tid >> 6;
    const int wm   = (w & 1) * 64;
    const int wn   = (w >> 1) * 64;
    const int l15  = lane & 15;
    const int lhi  = lane >> 4;
    const int co   = (lhi ^ ((l15 >> 1) & 3)) << 3;

    const int lid = bid >> 3;
    const int mt  = (bid & 7) * 64 + lid / 5;
    const int nt  = lid % 5;
    const int m0  = mt * 128;
    const int n0  = nt * 128;

    if (tid < 128) s_q[tid] = qv[mt * 128 + tid];   // drained by prologue vmcnt(0)

    auto stage = [&](int k0, char* buf) {       // 4 vm-instrs per wave
        #pragma unroll
        for (int t = 0; t < 2; ++t) {
            int ci  = t * 256 + tid;
            int row = ci >> 2;
            int kc  = (ci & 3) ^ ((row >> 1) & 3);
            llds16(A  + (size_t)(m0 + row) * lda + k0 + kc * 8,
                   buf + (size_t)(t * 256 + w * 64) * 16);
            llds16(Bt + (size_t)(n0 + row) * ldb + k0 + kc * 8,
                   buf + 8192 + (size_t)(t * 256 + w * 64) * 16);
        }
    };

    const int nk = K >> 5;     // 19 (odd; Pm placement relies on this)
    f32x4 acc[4][4] = {};
    stage(0, regA);
    asm volatile("s_waitcnt vmcnt(0)" ::: "memory");
    __syncthreads();

    for (int k = 0; k < nk; ++k) {
        RAW_BARRIER();                                   // #1
        if (k + 1 < nk) {
            stage((k + 1) << 5, regA + ((k + 1) & 1) * 16384);
        } else {
            // Pm stage into [17408, 35840): 1152 chunks (4x256 + 128),
            // queued BEHIND stage(nk-1) so vmcnt(4) below drains the stage.
            #pragma unroll
            for (int i = 0; i < 4; ++i)
                llds16(Pmg + (size_t)mt * (128 * PMS) + (size_t)(i * 256 + tid) * 8,
                       (char*)Pm + (size_t)(i * 256 + w * 64) * 16);
            if (w < 2)
                llds16(Pmg + (size_t)mt * (128 * PMS) + (size_t)(1024 + w * 64 + lane) * 8,
                       (char*)Pm + (size_t)(1024 + w * 64) * 16);
        }
        asm volatile("s_waitcnt vmcnt(4)" ::: "memory"); // stage(k) landed
        RAW_BARRIER();                                   // #2

        __bf16* As = (__bf16*)(regA + (k & 1) * 16384);
        __bf16* Bs = As + 4096;
        bf16x8 af[4], bg[4];
        #pragma unroll
        for (int i = 0; i < 4; ++i)
            af[i] = *(bf16x8*)(As + (wm + i * 16 + l15) * 32 + co);
        #pragma unroll
        for (int j = 0; j < 4; ++j)
            bg[j] = *(bf16x8*)(Bs + (wn + j * 16 + l15) * 32 + co);
        #pragma unroll
        for (int i = 0; i < 4; ++i)
            #pragma unroll
            for (int j = 0; j < 4; ++j)
                acc[i][j] = __builtin_amdgcn_mfma_f32_16x16x32_bf16(
                    af[i], bg[j], acc[i][j], 0, 0, 0);
    }
    __syncthreads();   // full drain: Pm landed, all compute done, Ts overlay safe

    const int g  = w & 1;
    const int nb = w >> 1;
    #pragma unroll
    for (int h = 0; h < 2; ++h) {
        if (wn == h * 64) {
            #pragma unroll
            for (int i = 0; i < 4; ++i)
                #pragma unroll
                for (int j = 0; j < 4; ++j) {
                    int c_local = j * 16 + l15;
                    int rbase   = wm + i * 16 + lhi * 4;
                    bf16x4 pk;
                    #pragma unroll
                    for (int e = 0; e < 4; ++e) pk[e] = (__bf16)acc[i][j][e];
                    *(bf16x4*)(Ts + c_local * 136 + rbase) = pk;
                }
        }
        __syncthreads();

        f32x4 acc2[4][2] = {};
        #pragma unroll
        for (int k0 = 0; k0 < 64; k0 += 32) {
            bf16x8 pa[4], hb[2];
            #pragma unroll
            for (int i = 0; i < 4; ++i)
                pa[i] = *(bf16x8*)(Pm + (g * 64 + i * 16 + l15) * PMS + k0 + lhi * 8);
            #pragma unroll
            for (int j = 0; j < 2; ++j)
                hb[j] = *(bf16x8*)(Ts + (nb * 32 + j * 16 + l15) * 136
                                      + g * 64 + k0 + lhi * 8);
            #pragma unroll
            for (int i = 0; i < 4; ++i)
                #pragma unroll
                for (int j = 0; j < 2; ++j)
                    acc2[i][j] = __builtin_amdgcn_mfma_f32_16x16x32_bf16(
                        pa[i], hb[j], acc2[i][j], 0, 0, 0);
        }
        #pragma unroll
        for (int j = 0; j < 2; ++j) {
            int col = n0 + h * 64 + nb * 32 + j * 16 + l15;
            float bv = (col < 600) ? bias[col] : 0.f;
            float yp = 0.f;
            #pragma unroll
            for (int i = 0; i < 4; ++i)
                #pragma unroll
                for (int e = 0; e < 4; ++e) {
                    float v = fmaxf(acc2[i][j][e] + bv, 0.f);   // relu
                    yp += s_q[g * 64 + i * 16 + lhi * 4 + e] * v;
                }
            yp += __shfl_xor(yp, 16, 64);
            yp += __shfl_xor(yp, 32, 64);
            if (lhi == 0 && col < FP)
                Y[(size_t)(mt * 2 + g) * FP + col] = __float2bfloat16(yp);
        }
        __syncthreads();
    }
}

// ===========================================================================
// Mega prep: [WT transposes | timestep emb | pair prep (Pmg,qv) | PX0 branch]
// ===========================================================================
struct WtJob  { const float* src; bf16* dst; int Ksrc, Nsrc, Kp, Np, blk0; };
struct PrepArgs {
    WtJob j[9];
    int nwt, te0, pp0, xtr0;
    const int*   ei;
    const float* ts;
    const float* xin; const float* Wtr; const float* btr; const float* mask;
    bf16* TE; bf16* Pmg; float* qv; bf16* PX0;
};

__global__ __launch_bounds__(256) void k_prep(PrepArgs a)
{
    __shared__ __align__(16) char sm[35840];
    const int bx  = blockIdx.x;
    const int tid = threadIdx.x;

    if (bx < a.nwt) {
        int ji = 0;
        while (ji < 8 && bx >= a.j[ji + 1].blk0) ++ji;
        WtJob jb = a.j[ji];
        int t  = bx - jb.blk0;
        int kt = (jb.Kp + 63) >> 6;
        int ti = t % kt, tj = t / kt;
        int kg0 = ti * 64, ng0 = tj * 64;
        float (*T)[65] = (float(*)[65])sm;
        #pragma unroll 4
        for (int r = 0; r < 16; ++r) {
            int kl = (tid >> 6) + r * 4, nl = tid & 63;
            int kg = kg0 + kl, ng = ng0 + nl;
            T[kl][nl] = (kg < jb.Ksrc && ng < jb.Nsrc)
                        ? jb.src[(size_t)kg * jb.Nsrc + ng] : 0.f;
        }
        __syncthreads();
        #pragma unroll 4
        for (int r = 0; r < 16; ++r) {
            int nl = (tid >> 6) + r * 4, kl = tid & 63;
            int ng = ng0 + nl, kg = kg0 + kl;
            if (ng < jb.Np && kg < jb.Kp)
                jb.dst[(size_t)ng * jb.Kp + kg] = __float2bfloat16(T[kl][nl]);
        }
    } else if (bx < a.pp0) {
        int idx = (bx - a.te0) * 256 + tid;
        int b = idx >> 7, jj = idx & 127;
        float tt = a.ts[b];
        int h = jj & 63;
        float freq = expf(-9.210340371976184f * (float)h / 64.f);  // ln(10000)
        float ang = tt * freq;
        a.TE[idx] = __float2bfloat16((jj < 64) ? cosf(ang) : sinf(ang));
    } else if (bx < a.xtr0) {
        // ---------- pair prep: P matrix (bf16, PMS stride) + q vector ----------
        int pr = bx - a.pp0;
        float* Pf   = (float*)sm;
        int*   cnt  = (int*)(sm + 32768);
        float* sQ   = (float*)(sm + 33280);
        float* sI   = (float*)(sm + 33792);
        float* sIvd = (float*)(sm + 34304);

        for (int idx = tid; idx < 8192; idx += 256) Pf[idx] = 0.f;
        if (tid < 128) cnt[tid] = 0;
        __syncthreads();
        for (int e = tid; e < 2 * EPG; e += 256) {
            int g  = (e >= EPG);
            int eg = (2 * pr + g) * EPG + (e - g * EPG);
            int ld = (a.ei[E + eg] & 63) + g * 64;
            atomicAdd(&cnt[ld], 1);
        }
        __syncthreads();
        if (tid < 128) {
            float d = (float)cnt[tid] + 1.0f;
            float iv = 1.f / d;
            sIvd[tid] = iv;
            sI[tid]   = rsqrtf(d);
            sQ[tid]   = iv;
        }
        __syncthreads();
        for (int e = tid; e < 2 * EPG; e += 256) {
            int g   = (e >= EPG);
            int eg  = (2 * pr + g) * EPG + (e - g * EPG);
            int lsl = a.ei[eg] & 63;
            int ldl = a.ei[E + eg] & 63;
            float cf = sI[g * 64 + lsl] * sI[g * 64 + ldl];
            atomicAdd(&Pf[(g * 64 + ldl) * 64 + lsl], cf);
            atomicAdd(&sQ[g * 64 + lsl], cf);
        }
        __syncthreads();
        if (tid < 128) {
            Pf[tid * 64 + (tid & 63)] += sIvd[tid];
            a.qv[pr * 128 + tid] = sQ[tid] * (1.f / 64.f);
        }
        __syncthreads();
        for (int idx = tid; idx < 128 * PMS; idx += 256) {
            int r = idx / PMS, k = idx - r * PMS;
            float v = (k < 64) ? Pf[r * 64 + k] : 0.f;
            a.Pmg[(size_t)pr * (128 * PMS) + idx] = __float2bfloat16(v);
        }
    } else {
        // ---------- PX0 branch (per graph) ----------
        int g = bx - a.xtr0;
        float* Pf  = (float*)sm;                 // 64*64 fp32 [0,16384); Ws overlays later
        float* Ws  = (float*)sm;                 // 19*304 fp32 [0,23104)
        float* xm  = (float*)(sm + 23104);       // 64*20 (col 19 = mask)
        float* xa  = (float*)(sm + 28224);       // 64*20 (col 19 = ba)
        float* isqv= (float*)(sm + 33344);       // 64
        float* ivdv= (float*)(sm + 33600);       // 64
        int*   cnt = (int*)  (sm + 33856);       // 64
        float* sb  = (float*)(sm + 34112);       // 304 fp32 -> ends 35328

        for (int idx = tid; idx < 4096; idx += 256) Pf[idx] = 0.f;
        if (tid < 64) cnt[tid] = 0;
        __syncthreads();
        for (int e = tid; e < EPG; e += 256)
            atomicAdd(&cnt[a.ei[E + g * EPG + e] & 63], 1);
        __syncthreads();
        if (tid < 64) {
            float d = (float)cnt[tid] + 1.0f;
            ivdv[tid] = 1.f / d;
            isqv[tid] = rsqrtf(d);
        }
        __syncthreads();
        for (int e = tid; e < EPG; e += 256) {
            int ls = a.ei[g * EPG + e] & 63;
            int ld = a.ei[E + g * EPG + e] & 63;
            atomicAdd(&Pf[ld * 64 + ls], isqv[ls] * isqv[ld]);
        }
        // xm load (independent of P)
        for (int idx = tid; idx < 64 * 20; idx += 256) {
            int n = idx / 20, j = idx - n * 20;
            float mv = a.mask[g * 64 + n];
            xm[idx] = (j < 19) ? mv * a.xin[(size_t)(g * 64 + n) * 19 + j] : mv;
        }
        __syncthreads();
        if (tid < 64) Pf[tid * 64 + tid] += ivdv[tid];
        __syncthreads();
        // xa[r][j] = sum_s Pf[r][s] * xm[s][j]  (j=19 gives ba)
        for (int idx = tid; idx < 64 * 20; idx += 256) {
            int r = idx / 20, j = idx - r * 20;
            float s = 0.f;
            #pragma unroll 8
            for (int s2 = 0; s2 < 64; ++s2)
                s += Pf[r * 64 + s2] * xm[s2 * 20 + j];
            xa[idx] = s;
        }
        __syncthreads();
        // Ws/sb load (Pf dead)
        for (int idx = tid; idx < 19 * 304; idx += 256) {
            int k = idx / 304, c = idx - k * 304;
            Ws[idx] = (c < 300) ? a.Wtr[k * 300 + c] : 0.f;
        }
        for (int c = tid; c < 304; c += 256)
            sb[c] = (c < 300) ? a.btr[c] : 0.f;
        __syncthreads();
        // PX0[r][c] = sum_j xa[r][j]*Ws[j][c] + ba[r]*sb[c]
        int n  = tid >> 2;
        int c0 = tid & 3;
        float ba = xa[n * 20 + 19];
        for (int c = c0; c < 304; c += 4) {
            float acc = ba * sb[c];
            #pragma unroll
            for (int k = 0; k < 19; ++k)
                acc += xa[n * 20 + k] * Ws[k * 304 + c];
            a.PX0[(size_t)(g * 64 + n) * KP1 + c] = __float2bfloat16(acc);
        }
        // zero cols 304..319
        bf16x8 z = {};
        for (int idx = tid; idx < 64 * 2; idx += 256) {
            int nn = idx >> 1, jv = idx & 1;
            *(bf16x8*)((__bf16*)a.PX0 + (size_t)(g * 64 + nn) * KP1 + 304 + jv * 8) = z;
        }
    }
}

// LayerNorm over 300 dims + affine, fp32 out; fused text passthrough copy
__global__ __launch_bounds__(256) void k_ln_copy(const float* __restrict__ G,
                                                 const float* __restrict__ lg,
                                                 const float* __restrict__ lb,
                                                 const float* __restrict__ text,
                                                 float* __restrict__ out)
{
    int r = blockIdx.x;
    int tid = threadIdx.x;
    __shared__ float red[4];
    __shared__ float smu, svar;

    float v0 = (tid < 300) ? G[r * 300 + tid] : 0.f;
    float v1 = (tid + 256 < 300) ? G[r * 300 + tid + 256] : 0.f;
    float s = v0 + v1;
    #pragma unroll
    for (int o = 32; o > 0; o >>= 1) s += __shfl_down(s, o, 64);
    if ((tid & 63) == 0) red[tid >> 6] = s;
    __syncthreads();
    if (tid == 0) smu = (red[0] + red[1] + red[2] + red[3]) * (1.f / 300.f);
    __syncthreads();
    float mu = smu;
    float d0 = (tid < 300) ? v0 - mu : 0.f;
    float d1 = (tid + 256 < 300) ? v1 - mu : 0.f;
    s = d0 * d0 + d1 * d1;
    #pragma unroll
    for (int o = 32; o > 0; o >>= 1) s += __shfl_down(s, o, 64);
    if ((tid & 63) == 0) red[tid >> 6] = s;
    __syncthreads();
    if (tid == 0) svar = (red[0] + red[1] + red[2] + red[3]) * (1.f / 300.f);
    __syncthreads();
    float rstd = rsqrtf(svar + 1e-5f);
    if (tid < 300)
        out[r * 300 + tid] = d0 * rstd * lg[tid] + lb[tid];
    if (tid + 256 < 300)
        out[r * 300 + tid + 256] = d1 * rstd * lg[tid + 256] + lb[tid + 256];
    float* o2 = out + (size_t)B * 300;
    for (int c = tid; c < 300; c += 256)
        o2[(size_t)r * 300 + c] = text[(size_t)r * 300 + c];
}

// ---------------------------------------------------------------------------
extern "C" void kernel_launch(void* const* d_in, const int* in_sizes, int n_in,
                              void* d_out, int out_size, void* d_ws, size_t ws_size,
                              hipStream_t stream)
{
    const float* x_in  = (const float*)d_in[0];
    const int*   ei    = (const int*)d_in[1];
    const float* text  = (const float*)d_in[3];
    const float* tst   = (const float*)d_in[4];
    const float* mask  = (const float*)d_in[5];
    const float* W_tr  = (const float*)d_in[6];
    const float* b_tr  = (const float*)d_in[7];
    const float* W_c1  = (const float*)d_in[8];
    const float* b_c1  = (const float*)d_in[9];
    const float* W_c2  = (const float*)d_in[10];
    const float* b_c2  = (const float*)d_in[11];
    const float* W_c3  = (const float*)d_in[12];
    const float* b_c3  = (const float*)d_in[13];
    const float* W_h1  = (const float*)d_in[14];
    const float* b_h1  = (const float*)d_in[15];
    const float* W_h2  = (const float*)d_in[16];
    const float* b_h2  = (const float*)d_in[17];
    const float* W_h3  = (const float*)d_in[18];
    const float* b_h3  = (const float*)d_in[19];
    const float* ln_g  = (const float*)d_in[20];
    const float* ln_b  = (const float*)d_in[21];
    const float* W_t1  = (const float*)d_in[22];
    const float* b_t1  = (const float*)d_in[23];
    const float* W_t2  = (const float*)d_in[24];
    const float* b_t2  = (const float*)d_in[25];
    const float* W_e   = (const float*)d_in[26];
    const float* b_e   = (const float*)d_in[27];

    // workspace carve (256B aligned) — ~150 MB
    char* w = (char*)d_ws;
    size_t off = 0;
    auto carve = [&](size_t bytes) {
        void* p = w + off;
        off += (bytes + 255) & ~(size_t)255;
        return p;
    };
    bf16*  PX0    = (bf16*) carve((size_t)BN * KP1 * 2);     // 42 MB
    bf16*  X1     = (bf16*) carve((size_t)BN * FP * 2);      // 79.7 MB
    bf16*  Wb1    = (bf16*) carve((size_t)640 * KP1 * 2);
    bf16*  Wb2    = (bf16*) carve((size_t)640 * FP * 2);
    bf16*  Wb3    = (bf16*) carve((size_t)640 * FP * 2);
    bf16*  Wt1t   = (bf16*) carve((size_t)512 * 128 * 2);
    bf16*  Wt2t   = (bf16*) carve((size_t)512 * 512 * 2);
    bf16*  Wet    = (bf16*) carve((size_t)3072 * 512 * 2);
    bf16*  Wh1t   = (bf16*) carve((size_t)640 * FP * 2);
    bf16*  Wh2t   = (bf16*) carve((size_t)640 * FP * 2);
    bf16*  Wh3t   = (bf16*) carve((size_t)384 * FP * 2);
    bf16*  TE     = (bf16*) carve((size_t)B * 128 * 2);
    bf16*  A1b    = (bf16*) carve((size_t)B * 512 * 2);
    bf16*  A2b    = (bf16*) carve((size_t)B * 512 * 2);
    bf16*  EO     = (bf16*) carve((size_t)B * 3000 * 2);
    bf16*  Yv     = (bf16*) carve((size_t)B * FP * 2);
    bf16*  G0     = (bf16*) carve((size_t)B * FP * 2);
    bf16*  G1     = (bf16*) carve((size_t)B * FP * 2);
    bf16*  G2     = (bf16*) carve((size_t)B * FP * 2);
    float* G3     = (float*)carve((size_t)B * 300 * 4);
    bf16*  Pmg    = (bf16*) carve((size_t)512 * 128 * PMS * 2);  // 9.4 MB
    float* qv     = (float*)carve((size_t)BN * 4);
    (void)ws_size; (void)in_sizes; (void)n_in; (void)out_size;

    float* out = (float*)d_out;

    // --- phase A: one mega prep launch ---
    PrepArgs pa;
    struct JD { const float* s; bf16* d; int Ks, Ns, Kp, Np; };
    JD jd[9] = {
        { W_c1, Wb1,  300, 600,  KP1, 640 },
        { W_c2, Wb2,  600, 600,  FP,  640 },
        { W_c3, Wb3,  600, 600,  FP,  640 },
        { W_t1, Wt1t, 128, 512,  128, 512 },
        { W_t2, Wt2t, 512, 512,  512, 512 },
        { W_e,  Wet,  512, 3000, 512, 3072 },
        { W_h1, Wh1t, 600, 600,  FP,  640 },
        { W_h2, Wh2t, 600, 600,  FP,  640 },
        { W_h3, Wh3t, 600, 300,  FP,  384 },
    };
    int cum = 0;
    for (int i = 0; i < 9; ++i) {
        int kt = (jd[i].Kp + 63) >> 6, nt = (jd[i].Np + 63) >> 6;
        pa.j[i] = { jd[i].s, jd[i].d, jd[i].Ks, jd[i].Ns, jd[i].Kp, jd[i].Np, cum };
        cum += kt * nt;
    }
    pa.nwt  = cum;
    pa.te0  = cum;       cum += (B * 128) / 256;
    pa.pp0  = cum;       cum += B / 2;
    pa.xtr0 = cum;       cum += B;
    pa.ei = ei; pa.ts = tst;
    pa.xin = x_in; pa.Wtr = W_tr; pa.btr = b_tr; pa.mask = mask;
    pa.TE = TE; pa.Pmg = Pmg; pa.qv = qv; pa.PX0 = PX0;
    k_prep<<<cum, 256, 0, stream>>>(pa);

    // --- conv1 as plain GEMM (+hidden t1: A1b = relu(TE @ Wt1t^T + b_t1)) ---
    conv1_gemm<<<NCONV + 64, 256, 0, stream>>>(
        PX0, Wb1, b_c1, X1,
        TE, 128, Wt1t, 128, b_t1, A1b, 512, 512, 128, 4);

    // --- conv2+conv3+pool (+hidden t2: A2b = relu(A1b @ Wt2t^T + b_t2)) ---
    conv_fused_q<<<NCONV + 64, 256, 0, stream>>>(
        X1, FP, FP, Wb2, FP, Pmg, b_c2, qv, Yv,
        A1b, 512, Wt2t, 512, b_t2, A2b, 512, 512, 512, 4);

    // --- EO = A2b @ Wet^T + b_e (384 blocks) || G0 = Yv @ Wb3^T + b_c3 (80) ---
    k_two_gemms<<<464, 256, 0, stream>>>(A2b, Wet, b_e, EO, Yv, Wb3, b_c3, G0);

    // --- h-layers with FiLM (64-row tiles) ---
    gemm64<true, true, bf16><<<dim3(16, 5), 256, 0, stream>>>(
        G0, FP, Wh1t, FP, b_h1, G1, FP, 600, EO + 0, EO + 600, 3000, FP);
    gemm64<true, true, bf16><<<dim3(16, 5), 256, 0, stream>>>(
        G1, FP, Wh2t, FP, b_h2, G2, FP, 600, EO + 1200, EO + 1800, 3000, FP);
    gemm64<false, true, float><<<dim3(16, 3), 256, 0, stream>>>(
        G2, FP, Wh3t, FP, b_h3, G3, 300, 300, EO + 2400, EO + 2700, 3000, FP);

    // --- layer norm + text passthrough ---
    k_ln_copy<<<B, 256, 0, stream>>>(G3, ln_g, ln_b, text, out);
}